// Round 1
// baseline (520.104 us; speedup 1.0000x reference)
//
#include <hip/hip_runtime.h>
#include <stdint.h>

#define DIM 128
#define RQ  131072
#define BB  1024
#define NNB 10
#define QEL ((size_t)DIM * RQ)   // 16777216 elements per queue

typedef short short8 __attribute__((ext_vector_type(8)));   // 8 bf16 (4 VGPRs)
typedef float f32x4  __attribute__((ext_vector_type(4)));

__device__ __forceinline__ unsigned short f2bf(float x) {
  union { float f; unsigned u; } v; v.f = x;
  unsigned r = v.u + 0x7FFFu + ((v.u >> 16) & 1u);   // RNE
  return (unsigned short)(r >> 16);
}
// 16-B-chunk XOR swizzle (low 3 bits) — conflict-free LDS without padding
__device__ __forceinline__ int swz16(int key, int chunk) {
  return (chunk & ~7) | ((chunk ^ key) & 7);
}

// ---------------- K1: row-normalize feats; bf16 copies; enqueue transpose; zero loss ----
__global__ __launch_bounds__(128) void k_norm(const float* __restrict__ fX,
                                              const float* __restrict__ fY,
                                              float* __restrict__ out,
                                              unsigned short* __restrict__ fbf) {
  const int b = blockIdx.x;            // 0..2047
  const int tensor = b >> 10;
  const int r = b & 1023;
  const float* src = tensor ? fY : fX;
  const int d = threadIdx.x;           // 0..127
  float v = src[(size_t)r * DIM + d];
  float s2 = v * v;
  #pragma unroll
  for (int o = 32; o; o >>= 1) s2 += __shfl_xor(s2, o, 64);
  __shared__ float wsum[2];
  if ((threadIdx.x & 63) == 0) wsum[threadIdx.x >> 6] = s2;
  __syncthreads();
  float nv = v / sqrtf(wsum[0] + wsum[1]);
  fbf[(size_t)tensor * BB * DIM + (size_t)r * DIM + d] = f2bf(nv);
  // new_queue[:, :B] = f.T  (d_out+1 base; scattered but tiny: 256K stores)
  out[1 + (size_t)tensor * QEL + (size_t)d * RQ + r] = nv;
  if (b == 0 && d == 0) out[0] = 0.0f;
}

// ---------------- K2: queue copy (cols >= B) + bf16 transpose qT[n][k] ----------------
__global__ __launch_bounds__(256) void k_qcopy(const float* __restrict__ qX,
                                               const float* __restrict__ qY,
                                               float* __restrict__ out,
                                               unsigned short* __restrict__ qT) {
  __shared__ uint32_t lds[128 * 65];   // [c][d2] stride 65 -> banks (c+d2)%32, 2-way free
  const int qi = blockIdx.y;
  const float* qsrc = qi ? qY : qX;
  float* o = out + 1 + (size_t)qi * QEL;
  unsigned short* tdst = qT + (size_t)qi * QEL;
  const int cb = blockIdx.x * 128;
  const int tid = threadIdx.x;
  const int c4 = tid & 31;             // c = c4*4 + j
  const int d2b = tid >> 5;            // 0..7
  const bool docopy = (cb >= BB);      // first 8 blocks: columns come from k_norm
  #pragma unroll
  for (int i = 0; i < 8; ++i) {
    int d2 = d2b + 8 * i;              // 0..63 (d pair)
    int d0 = 2 * d2;
    size_t base0 = (size_t)d0 * RQ + cb + c4 * 4;
    float4 r0 = *(const float4*)(qsrc + base0);
    float4 r1 = *(const float4*)(qsrc + base0 + RQ);
    if (docopy) {
      o[base0 + 0] = r0.x; o[base0 + 1] = r0.y; o[base0 + 2] = r0.z; o[base0 + 3] = r0.w;
      o[base0 + RQ + 0] = r1.x; o[base0 + RQ + 1] = r1.y;
      o[base0 + RQ + 2] = r1.z; o[base0 + RQ + 3] = r1.w;
    }
    uint32_t p0 = (uint32_t)f2bf(r0.x) | ((uint32_t)f2bf(r1.x) << 16);
    uint32_t p1 = (uint32_t)f2bf(r0.y) | ((uint32_t)f2bf(r1.y) << 16);
    uint32_t p2 = (uint32_t)f2bf(r0.z) | ((uint32_t)f2bf(r1.z) << 16);
    uint32_t p3 = (uint32_t)f2bf(r0.w) | ((uint32_t)f2bf(r1.w) << 16);
    lds[(c4 * 4 + 0) * 65 + d2] = p0;
    lds[(c4 * 4 + 1) * 65 + d2] = p1;
    lds[(c4 * 4 + 2) * 65 + d2] = p2;
    lds[(c4 * 4 + 3) * 65 + d2] = p3;
  }
  __syncthreads();
  #pragma unroll
  for (int i = 0; i < 8; ++i) {
    int g = tid + 256 * i;             // 16-B chunk id
    int c = g >> 4, k = g & 15;
    uint4 vv;
    vv.x = lds[c * 65 + k * 4 + 0];
    vv.y = lds[c * 65 + k * 4 + 1];
    vv.z = lds[c * 65 + k * 4 + 2];
    vv.w = lds[c * 65 + k * 4 + 3];
    *(uint4*)(tdst + (size_t)(cb + c) * DIM + k * 8) = vv;   // coalesced 1 KB/instr
  }
}

// ---------------- K3: GEMM1 (f @ queue) + per-(row,32-col) argmax candidates ----------
__global__ __launch_bounds__(256, 2) void k_gemm1(const unsigned short* __restrict__ fbf,
                                                  const unsigned short* __restrict__ qT,
                                                  float2* __restrict__ cand) {
  __shared__ char smem[65536];         // As 32K + Bs 32K; reused as CT 64K
  const int loss = blockIdx.z;
  const int mt = blockIdx.y;           // 0..7
  const int nt = blockIdx.x;           // 0..1023
  const unsigned short* A  = fbf + (size_t)loss * BB * DIM + (size_t)mt * 128 * DIM;
  const unsigned short* Bq = qT + (size_t)(1 - loss) * QEL + (size_t)nt * 128 * DIM;
  char* As = smem;
  char* Bs = smem + 32768;
  const int tid = threadIdx.x;
  #pragma unroll
  for (int i = 0; i < 8; ++i) {        // both tiles contiguous 32 KB in global
    int ch = tid + 256 * i;
    int row = ch >> 4, c16 = ch & 15;
    int p = swz16(row, c16);
    uint4 va = *(const uint4*)(A + (size_t)ch * 8);
    *(uint4*)(As + row * 256 + p * 16) = va;
    uint4 vb = *(const uint4*)(Bq + (size_t)ch * 8);
    *(uint4*)(Bs + row * 256 + p * 16) = vb;
  }
  __syncthreads();
  const int w = tid >> 6, lane = tid & 63;
  const int q = lane >> 4, l16 = lane & 15;
  const int wr = (w >> 1) * 64, wc = (w & 1) * 64;
  f32x4 zero = {0.f, 0.f, 0.f, 0.f};
  f32x4 acc[4][4];
  #pragma unroll
  for (int mi = 0; mi < 4; ++mi)
    #pragma unroll
    for (int ni = 0; ni < 4; ++ni) acc[mi][ni] = zero;
  #pragma unroll
  for (int kk = 0; kk < 4; ++kk) {
    short8 a[4], b[4];
    #pragma unroll
    for (int mi = 0; mi < 4; ++mi) {
      int row = wr + mi * 16 + l16;
      a[mi] = *(const short8*)(As + row * 256 + swz16(row, kk * 4 + q) * 16);
    }
    #pragma unroll
    for (int ni = 0; ni < 4; ++ni) {
      int row = wc + ni * 16 + l16;
      b[ni] = *(const short8*)(Bs + row * 256 + swz16(row, kk * 4 + q) * 16);
    }
    #pragma unroll
    for (int mi = 0; mi < 4; ++mi)
      #pragma unroll
      for (int ni = 0; ni < 4; ++ni)
        acc[mi][ni] = __builtin_amdgcn_mfma_f32_16x16x32_bf16(a[mi], b[ni], acc[mi][ni], 0, 0, 0);
  }
  __syncthreads();
  // CT[col][row] col-major (512 B/col), chunks (4 rows) swizzled by col -> b128 optimal
  char* CT = smem;
  #pragma unroll
  for (int mi = 0; mi < 4; ++mi) {
    #pragma unroll
    for (int ni = 0; ni < 4; ++ni) {
      int col = wc + ni * 16 + l16;
      int rc = ((wr + mi * 16) >> 2) + q;            // row/4
      *(f32x4*)(CT + col * 512 + swz16(col, rc) * 16) = acc[mi][ni];
    }
  }
  __syncthreads();
  if (tid < 128) {                     // 32 row-groups x 4 col-chunks(32)
    int rg = tid >> 2, ch2 = tid & 3;
    float bv0 = -1e30f, bv1 = -1e30f, bv2 = -1e30f, bv3 = -1e30f;
    int bi0 = 0, bi1 = 0, bi2 = 0, bi3 = 0;
    #pragma unroll 8
    for (int i = 0; i < 32; ++i) {
      int col = ch2 * 32 + i;
      f32x4 cv = *(const f32x4*)(CT + col * 512 + swz16(col, rg) * 16);
      if (cv[0] > bv0) { bv0 = cv[0]; bi0 = col; }
      if (cv[1] > bv1) { bv1 = cv[1]; bi1 = col; }
      if (cv[2] > bv2) { bv2 = cv[2]; bi2 = col; }
      if (cv[3] > bv3) { bv3 = cv[3]; bi3 = col; }
    }
    // cand[loss][nt][row_global][ch2]
    float2* cb = cand + (size_t)loss * 4194304 + (size_t)nt * 4096
                      + (size_t)(mt * 128 + rg * 4) * 4 + ch2;
    int nb = nt * 128;
    cb[0]  = make_float2(bv0, __int_as_float(nb + bi0));
    cb[4]  = make_float2(bv1, __int_as_float(nb + bi1));
    cb[8]  = make_float2(bv2, __int_as_float(nb + bi2));
    cb[12] = make_float2(bv3, __int_as_float(nb + bi3));
  }
}

// ---------------- K4: per-row top-10 of 4096 candidates + gather nn rows --------------
__global__ __launch_bounds__(256) void k_merge(const float2* __restrict__ cand,
                                               const unsigned short* __restrict__ qT,
                                               unsigned short* __restrict__ nnf) {
  const int loss = blockIdx.y;
  const int row = blockIdx.x;
  const float2* cb = cand + (size_t)loss * 4194304 + (size_t)row * 4;
  const int tid = threadIdx.x;
  float v[16]; int ix[16];
  #pragma unroll
  for (int i = 0; i < 4; ++i) {
    const float2* p = cb + (size_t)(tid + 256 * i) * 4096;
    #pragma unroll
    for (int j = 0; j < 4; ++j) {
      float2 pr = p[j];
      v[i * 4 + j] = pr.x; ix[i * 4 + j] = __float_as_int(pr.y);
    }
  }
  __shared__ float sv[4]; __shared__ int si[4];
  __shared__ int winner;
  __shared__ int outw[NNB];
  for (int r = 0; r < NNB; ++r) {
    float mv = -1e30f; int mloc = 0;
    #pragma unroll
    for (int i = 0; i < 16; ++i) if (v[i] > mv) { mv = v[i]; mloc = i; }
    int gix = ix[mloc];
    #pragma unroll
    for (int o = 32; o; o >>= 1) {
      float ov = __shfl_xor(mv, o, 64);
      int   oi = __shfl_xor(gix, o, 64);
      if (ov > mv) { mv = ov; gix = oi; }
    }
    if ((tid & 63) == 0) { sv[tid >> 6] = mv; si[tid >> 6] = gix; }
    __syncthreads();
    if (tid == 0) {
      float bm = sv[0]; int bi = si[0];
      #pragma unroll
      for (int u = 1; u < 4; ++u) if (sv[u] > bm) { bm = sv[u]; bi = si[u]; }
      winner = bi; outw[r] = bi;
    }
    __syncthreads();
    int wn = winner;
    #pragma unroll
    for (int i = 0; i < 16; ++i) if (ix[i] == wn) v[i] = -3e38f;  // unique idx per row
    __syncthreads();
  }
  const unsigned short* qs = qT + (size_t)(1 - loss) * QEL;
  if (tid < 160) {                     // 10 neighbors x 16 chunks of 16 B
    int j = tid >> 4, k = tid & 15;
    int n = outw[j];
    uint4 vv = *(const uint4*)(qs + (size_t)n * DIM + k * 8);
    *(uint4*)(nnf + (size_t)loss * BB * NNB * DIM + (size_t)(row * NNB + j) * DIM + k * 8) = vv;
  }
}

// ---------------- K5: GEMM2 (f @ nn^T) * (1/TEMP) -> sim2 fp32 -----------------------
__global__ __launch_bounds__(256, 2) void k_gemm2(const unsigned short* __restrict__ fbf,
                                                  const unsigned short* __restrict__ nnf,
                                                  float* __restrict__ sim2) {
  __shared__ char smem[65536];
  const int loss = blockIdx.z;
  const int mt = blockIdx.y;           // 0..7
  const int nt = blockIdx.x;           // 0..79
  const unsigned short* A  = fbf + (size_t)loss * BB * DIM + (size_t)mt * 128 * DIM;
  const unsigned short* Bn = nnf + (size_t)loss * BB * NNB * DIM + (size_t)nt * 128 * DIM;
  float* outp = sim2 + (size_t)loss * 10485760 + (size_t)(mt * 128) * 10240 + nt * 128;
  char* As = smem;
  char* Bs = smem + 32768;
  const int tid = threadIdx.x;
  #pragma unroll
  for (int i = 0; i < 8; ++i) {
    int ch = tid + 256 * i;
    int row = ch >> 4, c16 = ch & 15;
    int p = swz16(row, c16);
    uint4 va = *(const uint4*)(A + (size_t)ch * 8);
    *(uint4*)(As + row * 256 + p * 16) = va;
    uint4 vb = *(const uint4*)(Bn + (size_t)ch * 8);
    *(uint4*)(Bs + row * 256 + p * 16) = vb;
  }
  __syncthreads();
  const int w = tid >> 6, lane = tid & 63;
  const int q = lane >> 4, l16 = lane & 15;
  const int wr = (w >> 1) * 64, wc = (w & 1) * 64;
  f32x4 zero = {0.f, 0.f, 0.f, 0.f};
  f32x4 acc[4][4];
  #pragma unroll
  for (int mi = 0; mi < 4; ++mi)
    #pragma unroll
    for (int ni = 0; ni < 4; ++ni) acc[mi][ni] = zero;
  #pragma unroll
  for (int kk = 0; kk < 4; ++kk) {
    short8 a[4], b[4];
    #pragma unroll
    for (int mi = 0; mi < 4; ++mi) {
      int row = wr + mi * 16 + l16;
      a[mi] = *(const short8*)(As + row * 256 + swz16(row, kk * 4 + q) * 16);
    }
    #pragma unroll
    for (int ni = 0; ni < 4; ++ni) {
      int row = wc + ni * 16 + l16;
      b[ni] = *(const short8*)(Bs + row * 256 + swz16(row, kk * 4 + q) * 16);
    }
    #pragma unroll
    for (int mi = 0; mi < 4; ++mi)
      #pragma unroll
      for (int ni = 0; ni < 4; ++ni)
        acc[mi][ni] = __builtin_amdgcn_mfma_f32_16x16x32_bf16(a[mi], b[ni], acc[mi][ni], 0, 0, 0);
  }
  __syncthreads();
  // Cs[row][col] row-major, 16-B chunks swizzled by row; scalar writes are 2-way free
  char* Cs = smem;
  #pragma unroll
  for (int mi = 0; mi < 4; ++mi)
    #pragma unroll
    for (int ni = 0; ni < 4; ++ni) {
      int col = wc + ni * 16 + l16;
      int cc = col >> 2, c3 = col & 3;
      #pragma unroll
      for (int r4 = 0; r4 < 4; ++r4) {
        int row = wr + mi * 16 + q * 4 + r4;
        *(float*)(Cs + row * 512 + swz16(row, cc) * 16 + c3 * 4) = acc[mi][ni][r4] * 10.0f;
      }
    }
  __syncthreads();
  #pragma unroll
  for (int i = 0; i < 16; ++i) {
    int g = tid + 256 * i;             // 128 rows x 32 chunks
    int r = g >> 5, k = g & 31;
    f32x4 vv = *(const f32x4*)(Cs + r * 512 + swz16(r, k) * 16);
    *(f32x4*)(outp + (size_t)r * 10240 + k * 4) = vv;
  }
}

// ---------------- K6: online-softmax row loss, atomic accumulate ----------------------
__global__ __launch_bounds__(256) void k_loss(const float* __restrict__ sim2,
                                              float* __restrict__ out) {
  const int loss = blockIdx.y;
  const int row = blockIdx.x;
  const float* sr = sim2 + (size_t)loss * 10485760 + (size_t)row * 10240;
  const int tid = threadIdx.x;
  float m = -3e38f, s = 0.f;
  for (int i = tid; i < 2560; i += 256) {
    float4 vv = *(const float4*)(sr + (size_t)i * 4);
    float m4 = fmaxf(fmaxf(vv.x, vv.y), fmaxf(vv.z, vv.w));
    if (m4 > m) { s *= __expf(m - m4); m = m4; }
    s += __expf(vv.x - m) + __expf(vv.y - m) + __expf(vv.z - m) + __expf(vv.w - m);
  }
  #pragma unroll
  for (int o = 32; o; o >>= 1) {
    float om = __shfl_xor(m, o, 64);
    float os = __shfl_xor(s, o, 64);
    float nm = fmaxf(m, om);
    s = s * __expf(m - nm) + os * __expf(om - nm);
    m = nm;
  }
  __shared__ float sm[4], ss[4];
  if ((tid & 63) == 0) { sm[tid >> 6] = m; ss[tid >> 6] = s; }
  __syncthreads();
  __shared__ float fm, fls;
  if (tid == 0) {
    float M = sm[0], S = ss[0];
    for (int u = 1; u < 4; ++u) {
      float nm = fmaxf(M, sm[u]);
      S = S * __expf(M - nm) + ss[u] * __expf(sm[u] - nm);
      M = nm;
    }
    fm = M; fls = logf(S);
  }
  __syncthreads();
  __shared__ float ps[NNB];
  if (tid < NNB) ps[tid] = sr[row * NNB + tid] - fm - fls;
  __syncthreads();
  if (tid == 0) {
    float t = 0.f;
    #pragma unroll
    for (int j = 0; j < NNB; ++j) t += ps[j];
    atomicAdd(out, -t * (1.0f / 1024.0f));
  }
}

// ---------------- launch --------------------------------------------------------------
// ws layout (bytes):
//   0         fbf   : 2 x 1024 x 128 bf16              =   524288
//   524288    qT    : 2 x 131072 x 128 bf16            = 67108864
//   67633152  nn    : 2 x 10240 x 128 bf16             =  5242880
//   72876032  cand  : 2 x 1024 x 1024 x 4 float2       = 67108864   (dead after k_merge)
//   72876032  sim2  : 2 x 1024 x 10240 f32 (overlaps)  = 83886080   -> end 156762112
extern "C" void kernel_launch(void* const* d_in, const int* in_sizes, int n_in,
                              void* d_out, int out_size, void* d_ws, size_t ws_size,
                              hipStream_t stream) {
  (void)in_sizes; (void)n_in; (void)out_size; (void)ws_size;
  const float* fX = (const float*)d_in[0];
  const float* fY = (const float*)d_in[1];
  const float* qX = (const float*)d_in[2];
  const float* qY = (const float*)d_in[3];
  float* out = (float*)d_out;
  char* ws = (char*)d_ws;
  unsigned short* fbf = (unsigned short*)(ws + 0);
  unsigned short* qT  = (unsigned short*)(ws + 524288);
  unsigned short* nnf = (unsigned short*)(ws + 67633152);
  float2* cand        = (float2*)(ws + 72876032);
  float* sim2         = (float*)(ws + 72876032);

  hipLaunchKernelGGL(k_norm,  dim3(2048),        dim3(128), 0, stream, fX, fY, out, fbf);
  hipLaunchKernelGGL(k_qcopy, dim3(1024, 2),     dim3(256), 0, stream, qX, qY, out, qT);
  hipLaunchKernelGGL(k_gemm1, dim3(1024, 8, 2),  dim3(256), 0, stream, fbf, qT, cand);
  hipLaunchKernelGGL(k_merge, dim3(1024, 2),     dim3(256), 0, stream, cand, qT, nnf);
  hipLaunchKernelGGL(k_gemm2, dim3(80, 8, 2),    dim3(256), 0, stream, fbf, nnf, sim2);
  hipLaunchKernelGGL(k_loss,  dim3(1024, 2),     dim3(256), 0, stream, sim2, out);
}

// Round 2
// 404.177 us; speedup vs baseline: 1.2868x; 1.2868x over previous
//
#include <hip/hip_runtime.h>
#include <hip/hip_fp16.h>
#include <stdint.h>

#define DIM 128
#define RQ  131072
#define BB  1024
#define NNB 10
#define QEL ((size_t)DIM * RQ)   // 16777216 elements per queue

typedef short short8 __attribute__((ext_vector_type(8)));   // 8 bf16 (4 VGPRs)
typedef float f32x4  __attribute__((ext_vector_type(4)));
typedef float f32x16 __attribute__((ext_vector_type(16)));
typedef unsigned short us4 __attribute__((ext_vector_type(4)));

__device__ __forceinline__ unsigned short f2bf(float x) {
  union { float f; unsigned u; } v; v.f = x;
  unsigned r = v.u + 0x7FFFu + ((v.u >> 16) & 1u);   // RNE
  return (unsigned short)(r >> 16);
}
// 16-B-chunk XOR swizzle (low 3 bits) — conflict-free LDS without padding
__device__ __forceinline__ int swz16(int key, int chunk) {
  return (chunk & ~7) | ((chunk ^ key) & 7);
}

// ---------------- K1: row-normalize feats; bf16 copies; enqueue transpose; zero loss ----
__global__ __launch_bounds__(128) void k_norm(const float* __restrict__ fX,
                                              const float* __restrict__ fY,
                                              float* __restrict__ out,
                                              unsigned short* __restrict__ fbf) {
  const int b = blockIdx.x;            // 0..2047
  const int tensor = b >> 10;
  const int r = b & 1023;
  const float* src = tensor ? fY : fX;
  const int d = threadIdx.x;           // 0..127
  float v = src[(size_t)r * DIM + d];
  float s2 = v * v;
  #pragma unroll
  for (int o = 32; o; o >>= 1) s2 += __shfl_xor(s2, o, 64);
  __shared__ float wsum[2];
  if ((threadIdx.x & 63) == 0) wsum[threadIdx.x >> 6] = s2;
  __syncthreads();
  float nv = v / sqrtf(wsum[0] + wsum[1]);
  fbf[(size_t)tensor * BB * DIM + (size_t)r * DIM + d] = f2bf(nv);
  out[1 + (size_t)tensor * QEL + (size_t)d * RQ + r] = nv;
  if (b == 0 && d == 0) out[0] = 0.0f;
}

// ---------------- K2: queue copy (cols >= B) + bf16 transpose qT[n][k] (chunk-swizzled) --
__global__ __launch_bounds__(256) void k_qcopy(const float* __restrict__ qX,
                                               const float* __restrict__ qY,
                                               float* __restrict__ out,
                                               unsigned short* __restrict__ qT) {
  __shared__ uint32_t lds[128 * 65];   // [c][d2] stride 65 -> banks (c+d2)%32
  const int qi = blockIdx.y;
  const float* qsrc = qi ? qY : qX;
  float* o = out + 1 + (size_t)qi * QEL;
  unsigned short* tdst = qT + (size_t)qi * QEL;
  const int cb = blockIdx.x * 128;
  const int tid = threadIdx.x;
  const int c4 = tid & 31;
  const int d2b = tid >> 5;
  const bool docopy = (cb >= BB);
  #pragma unroll
  for (int i = 0; i < 8; ++i) {
    int d2 = d2b + 8 * i;
    int d0 = 2 * d2;
    size_t base0 = (size_t)d0 * RQ + cb + c4 * 4;
    float4 r0 = *(const float4*)(qsrc + base0);
    float4 r1 = *(const float4*)(qsrc + base0 + RQ);
    if (docopy) {
      o[base0 + 0] = r0.x; o[base0 + 1] = r0.y; o[base0 + 2] = r0.z; o[base0 + 3] = r0.w;
      o[base0 + RQ + 0] = r1.x; o[base0 + RQ + 1] = r1.y;
      o[base0 + RQ + 2] = r1.z; o[base0 + RQ + 3] = r1.w;
    }
    uint32_t p0 = (uint32_t)f2bf(r0.x) | ((uint32_t)f2bf(r1.x) << 16);
    uint32_t p1 = (uint32_t)f2bf(r0.y) | ((uint32_t)f2bf(r1.y) << 16);
    uint32_t p2 = (uint32_t)f2bf(r0.z) | ((uint32_t)f2bf(r1.z) << 16);
    uint32_t p3 = (uint32_t)f2bf(r0.w) | ((uint32_t)f2bf(r1.w) << 16);
    lds[(c4 * 4 + 0) * 65 + d2] = p0;
    lds[(c4 * 4 + 1) * 65 + d2] = p1;
    lds[(c4 * 4 + 2) * 65 + d2] = p2;
    lds[(c4 * 4 + 3) * 65 + d2] = p3;
  }
  __syncthreads();
  #pragma unroll
  for (int i = 0; i < 8; ++i) {
    int g = tid + 256 * i;             // 16-B chunk id
    int c = g >> 4, k = g & 15;
    uint4 vv;
    vv.x = lds[c * 65 + k * 4 + 0];
    vv.y = lds[c * 65 + k * 4 + 1];
    vv.z = lds[c * 65 + k * 4 + 2];
    vv.w = lds[c * 65 + k * 4 + 3];
    // chunk-swizzled so gemm1's linear global_load_lds -> conflict-free ds_read_b128
    *(uint4*)(tdst + (size_t)(cb + c) * DIM + swz16(cb + c, k) * 8) = vv;
  }
}

// ---------------- K3: GEMM1 streaming 16 B-tiles, feat-in-regs, in-reg window argmax ----
__global__ __launch_bounds__(256, 2) void k_gemm1(const unsigned short* __restrict__ fbf,
                                                  const unsigned short* __restrict__ qT,
                                                  unsigned* __restrict__ cand) {
  __shared__ char smem[65536];         // 2 x 32KB B double-buffer
  const int ntg = blockIdx.x, mt = blockIdx.y, loss = blockIdx.z;
  const int tid = threadIdx.x;
  const int w = tid >> 6, l = tid & 63;
  const int l31 = l & 31, h = l >> 5;
  const int rw = (w >> 1) * 64;        // feat row base within WG tile
  const int cw = (w & 1) * 64;         // queue col base within B tile
  const unsigned short* qbase = qT + (size_t)(1 - loss) * QEL;
  const int nt0 = ntg * 16;

  // feat fragments (B-operand) held in registers for all 16 tiles
  short8 fq[2][8];
  {
    const unsigned short* A = fbf + (size_t)loss * BB * DIM + (size_t)(mt * 128 + rw) * DIM;
    #pragma unroll
    for (int nj = 0; nj < 2; ++nj)
      #pragma unroll
      for (int kk = 0; kk < 8; ++kk)
        fq[nj][kk] = *(const short8*)(A + (size_t)(nj * 32 + l31) * DIM + (2 * kk + h) * 8);
  }
  // prefetch tile 0 into buf 0
  {
    const unsigned short* g = qbase + (size_t)nt0 * 128 * DIM;
    #pragma unroll
    for (int i = 0; i < 8; ++i) {
      int gch = i * 256 + tid;
      __builtin_amdgcn_global_load_lds(
        (const __attribute__((address_space(1))) unsigned int*)(g + (size_t)gch * 8),
        (__attribute__((address_space(3))) unsigned int*)(smem + gch * 16), 16, 0, 0);
    }
  }

  for (int t = 0; t < 16; ++t) {
    const char* bufp = smem + (t & 1) * 32768;
    if (t == 0) __builtin_amdgcn_s_waitcnt(0x0F70);  // vmcnt(0)
    else        __builtin_amdgcn_s_waitcnt(0x0F72);  // vmcnt(2): 2 cand stores may stay in flight
    __asm__ volatile("" ::: "memory");
    __builtin_amdgcn_s_barrier();
    __asm__ volatile("" ::: "memory");
    if (t < 15) {                      // prefetch t+1 overlaps compute(t)
      const unsigned short* g = qbase + (size_t)(nt0 + t + 1) * 128 * DIM;
      char* nb = smem + ((t + 1) & 1) * 32768;
      #pragma unroll
      for (int i = 0; i < 8; ++i) {
        int gch = i * 256 + tid;
        __builtin_amdgcn_global_load_lds(
          (const __attribute__((address_space(1))) unsigned int*)(g + (size_t)gch * 8),
          (__attribute__((address_space(3))) unsigned int*)(nb + gch * 16), 16, 0, 0);
      }
    }
    f32x16 acc[2][2];
    #pragma unroll
    for (int nj = 0; nj < 2; ++nj)
      #pragma unroll
      for (int mi = 0; mi < 2; ++mi)
        #pragma unroll
        for (int r = 0; r < 16; ++r) acc[nj][mi][r] = 0.0f;
    #pragma unroll
    for (int kk = 0; kk < 8; ++kk) {
      short8 aq[2];
      #pragma unroll
      for (int mi = 0; mi < 2; ++mi) {
        int nq = cw + mi * 32 + l31;
        int c = 2 * kk + h;
        aq[mi] = *(const short8*)(bufp + nq * 256 + swz16(nq, c) * 16);
      }
      #pragma unroll
      for (int nj = 0; nj < 2; ++nj)
        #pragma unroll
        for (int mi = 0; mi < 2; ++mi)
          acc[nj][mi] = __builtin_amdgcn_mfma_f32_32x32x16_bf16(aq[mi], fq[nj][kk], acc[nj][mi], 0, 0, 0);
    }
    // epilogue: per feat-row argmax over this wave's 64 queue cols, packed key
    const int nt = nt0 + t;
    #pragma unroll
    for (int nj = 0; nj < 2; ++nj) {
      unsigned key = 0u;
      #pragma unroll
      for (int mi = 0; mi < 2; ++mi)
        #pragma unroll
        for (int r = 0; r < 16; ++r) {
          float v = acc[nj][mi][r] + 2.0f;      // > 0 -> raw bits are monotone
          unsigned c6 = (unsigned)(mi * 32 + (r & 3) + 8 * (r >> 2) + 4 * h);
          unsigned k2 = (__float_as_uint(v) & ~63u) | c6;
          key = key > k2 ? key : k2;
        }
      unsigned ko = (unsigned)__shfl_xor((int)key, 32, 64);
      key = key > ko ? key : ko;
      if (h == 0) {
        int row = mt * 128 + rw + nj * 32 + l31;
        cand[((size_t)loss * BB + row) * 2048 + (nt * 2 + (w & 1))] = key;
      }
    }
  }
}

// ---------------- K4: per-row top-10 of 2048 keys (wave per row) + nn gather ----------
__global__ __launch_bounds__(256) void k_merge(const unsigned* __restrict__ cand,
                                               const unsigned short* __restrict__ qT,
                                               unsigned short* __restrict__ nnf) {
  __shared__ unsigned ent[4][2048];    // 32KB entry cache, one slab per wave
  __shared__ int cols[4][16];
  const int loss = blockIdx.y;
  const int tid = threadIdx.x;
  const int wv = tid >> 6, l = tid & 63;
  const int row = blockIdx.x * 4 + wv;
  const uint4* cr = (const uint4*)(cand + ((size_t)loss * BB + row) * 2048);
  unsigned* E = ent[wv];
  unsigned kmax = 0; int imax = 0;
  #pragma unroll
  for (int it = 0; it < 8; ++it) {
    uint4 v = cr[l * 8 + it];          // coalesced 1KB/wave-instr
    int base = l * 32 + it * 4;
    *(uint4*)(&E[base]) = v;
    if (v.x > kmax) { kmax = v.x; imax = base + 0; }
    if (v.y > kmax) { kmax = v.y; imax = base + 1; }
    if (v.z > kmax) { kmax = v.z; imax = base + 2; }
    if (v.w > kmax) { kmax = v.w; imax = base + 3; }
  }
  for (int r = 0; r < NNB; ++r) {
    unsigned k = kmax; unsigned s = (unsigned)imax;
    #pragma unroll
    for (int o = 1; o < 64; o <<= 1) {
      unsigned ok = (unsigned)__shfl_xor((int)k, o, 64);
      unsigned os = (unsigned)__shfl_xor((int)s, o, 64);
      if (ok > k || (ok == k && os > s)) { k = ok; s = os; }
    }
    if (l == 0) cols[wv][r] = (int)(s * 64 + (k & 63u));   // global queue col
    if ((int)(s >> 5) == l) {          // owner lane: invalidate + rescan its 32
      E[s] = 0;
      kmax = 0; imax = l * 32;
      #pragma unroll
      for (int i = 0; i < 32; ++i) {
        unsigned kv = E[l * 32 + i];
        if (kv > kmax) { kmax = kv; imax = l * 32 + i; }
      }
    }
  }
  __syncthreads();
  // gather 10 neighbor rows (de-swizzling qT chunks) into plain nnf layout
  const unsigned short* qs = qT + (size_t)(1 - loss) * QEL;
  #pragma unroll
  for (int it = 0; it < 3; ++it) {
    int t2 = l + 64 * it;
    if (t2 < 160) {
      int j = t2 >> 4, kc = t2 & 15;
      int cj = cols[wv][j];
      uint4 v = *(const uint4*)(qs + (size_t)cj * DIM + swz16(cj, kc) * 8);
      *(uint4*)(nnf + ((size_t)loss * BB * NNB + (size_t)row * NNB + j) * DIM + kc * 8) = v;
    }
  }
}

// ---------------- K5: GEMM2 (f @ nn^T) * (1/TEMP) -> sim2 fp16 -----------------------
__global__ __launch_bounds__(256, 2) void k_gemm2(const unsigned short* __restrict__ fbf,
                                                  const unsigned short* __restrict__ nnf,
                                                  unsigned short* __restrict__ sim2) {
  __shared__ char smem[65536];
  const int loss = blockIdx.z;
  const int mt = blockIdx.y;           // 0..7
  const int nt = blockIdx.x;           // 0..79
  const unsigned short* A  = fbf + (size_t)loss * BB * DIM + (size_t)mt * 128 * DIM;
  const unsigned short* Bn = nnf + (size_t)loss * BB * NNB * DIM + (size_t)nt * 128 * DIM;
  unsigned short* outp = sim2 + (size_t)loss * 10485760 + (size_t)(mt * 128) * 10240 + nt * 128;
  char* As = smem;
  char* Bs = smem + 32768;
  const int tid = threadIdx.x;
  #pragma unroll
  for (int i = 0; i < 8; ++i) {
    int ch = tid + 256 * i;
    int row = ch >> 4, c16 = ch & 15;
    int p = swz16(row, c16);
    uint4 va = *(const uint4*)(A + (size_t)ch * 8);
    *(uint4*)(As + row * 256 + p * 16) = va;
    uint4 vb = *(const uint4*)(Bn + (size_t)ch * 8);
    *(uint4*)(Bs + row * 256 + p * 16) = vb;
  }
  __syncthreads();
  const int w = tid >> 6, lane = tid & 63;
  const int q = lane >> 4, l16 = lane & 15;
  const int wr = (w >> 1) * 64, wc = (w & 1) * 64;
  f32x4 zero = {0.f, 0.f, 0.f, 0.f};
  f32x4 acc[4][4];
  #pragma unroll
  for (int mi = 0; mi < 4; ++mi)
    #pragma unroll
    for (int ni = 0; ni < 4; ++ni) acc[mi][ni] = zero;
  #pragma unroll
  for (int kk = 0; kk < 4; ++kk) {
    short8 a[4], b[4];
    #pragma unroll
    for (int mi = 0; mi < 4; ++mi) {
      int row = wr + mi * 16 + l16;
      a[mi] = *(const short8*)(As + row * 256 + swz16(row, kk * 4 + q) * 16);
    }
    #pragma unroll
    for (int ni = 0; ni < 4; ++ni) {
      int row = wc + ni * 16 + l16;
      b[ni] = *(const short8*)(Bs + row * 256 + swz16(row, kk * 4 + q) * 16);
    }
    #pragma unroll
    for (int mi = 0; mi < 4; ++mi)
      #pragma unroll
      for (int ni = 0; ni < 4; ++ni)
        acc[mi][ni] = __builtin_amdgcn_mfma_f32_16x16x32_bf16(a[mi], b[ni], acc[mi][ni], 0, 0, 0);
  }
  __syncthreads();
  char* Cs = smem;
  #pragma unroll
  for (int mi = 0; mi < 4; ++mi)
    #pragma unroll
    for (int ni = 0; ni < 4; ++ni) {
      int col = wc + ni * 16 + l16;
      int cc = col >> 2, c3 = col & 3;
      #pragma unroll
      for (int r4 = 0; r4 < 4; ++r4) {
        int row = wr + mi * 16 + q * 4 + r4;
        *(float*)(Cs + row * 512 + swz16(row, cc) * 16 + c3 * 4) = acc[mi][ni][r4] * 10.0f;
      }
    }
  __syncthreads();
  #pragma unroll
  for (int i = 0; i < 16; ++i) {
    int g = tid + 256 * i;             // 128 rows x 32 chunks
    int r = g >> 5, k = g & 31;
    f32x4 vv = *(const f32x4*)(Cs + r * 512 + swz16(r, k) * 16);
    us4 h4;
    h4.x = __half_as_ushort(__float2half(vv[0]));
    h4.y = __half_as_ushort(__float2half(vv[1]));
    h4.z = __half_as_ushort(__float2half(vv[2]));
    h4.w = __half_as_ushort(__float2half(vv[3]));
    *(us4*)(outp + (size_t)r * 10240 + k * 4) = h4;
  }
}

// ---------------- K6: online-softmax row loss (fp16 sims), atomic accumulate ----------
__global__ __launch_bounds__(256) void k_loss(const unsigned short* __restrict__ sim2,
                                              float* __restrict__ out) {
  const int loss = blockIdx.y;
  const int row = blockIdx.x;
  const unsigned short* sr = sim2 + ((size_t)loss * BB + row) * 10240;
  const int tid = threadIdx.x;
  float m = -3e38f, s = 0.f;
  for (int i = tid; i < 1280; i += 256) {
    uint4 u = *(const uint4*)(sr + (size_t)i * 8);
    float f0 = __half2float(__ushort_as_half((unsigned short)(u.x & 0xFFFF)));
    float f1 = __half2float(__ushort_as_half((unsigned short)(u.x >> 16)));
    float f2 = __half2float(__ushort_as_half((unsigned short)(u.y & 0xFFFF)));
    float f3 = __half2float(__ushort_as_half((unsigned short)(u.y >> 16)));
    float f4 = __half2float(__ushort_as_half((unsigned short)(u.z & 0xFFFF)));
    float f5 = __half2float(__ushort_as_half((unsigned short)(u.z >> 16)));
    float f6 = __half2float(__ushort_as_half((unsigned short)(u.w & 0xFFFF)));
    float f7 = __half2float(__ushort_as_half((unsigned short)(u.w >> 16)));
    float m8 = fmaxf(fmaxf(fmaxf(f0, f1), fmaxf(f2, f3)), fmaxf(fmaxf(f4, f5), fmaxf(f6, f7)));
    if (m8 > m) { s *= __expf(m - m8); m = m8; }
    s += __expf(f0 - m) + __expf(f1 - m) + __expf(f2 - m) + __expf(f3 - m)
       + __expf(f4 - m) + __expf(f5 - m) + __expf(f6 - m) + __expf(f7 - m);
  }
  #pragma unroll
  for (int o = 32; o; o >>= 1) {
    float om = __shfl_xor(m, o, 64);
    float os = __shfl_xor(s, o, 64);
    float nm = fmaxf(m, om);
    s = s * __expf(m - nm) + os * __expf(om - nm);
    m = nm;
  }
  __shared__ float sm[4], ss[4];
  if ((tid & 63) == 0) { sm[tid >> 6] = m; ss[tid >> 6] = s; }
  __syncthreads();
  __shared__ float fm, fls;
  if (tid == 0) {
    float M = sm[0], S = ss[0];
    for (int u = 1; u < 4; ++u) {
      float nm = fmaxf(M, sm[u]);
      S = S * __expf(M - nm) + ss[u] * __expf(sm[u] - nm);
      M = nm;
    }
    fm = M; fls = logf(S);
  }
  __syncthreads();
  __shared__ float ps[NNB];
  if (tid < NNB)
    ps[tid] = __half2float(__ushort_as_half(sr[row * NNB + tid])) - fm - fls;
  __syncthreads();
  if (tid == 0) {
    float t = 0.f;
    #pragma unroll
    for (int j = 0; j < NNB; ++j) t += ps[j];
    atomicAdd(out, -t * (1.0f / 1024.0f));
  }
}

// ---------------- launch --------------------------------------------------------------
// ws layout (bytes):
//   0          fbf   : 2 x 1024 x 128 bf16             =   524288
//   524288     qT    : 2 x 131072 x 128 bf16 (swizzled)= 67108864  -> 67633152
//   67633152   nnf   : 2 x 10240 x 128 bf16            =  5242880  -> 72876032
//   72876032   cand  : 2 x 1024 x 2048 u32             = 16777216  -> 89653248
//   89653248   sim2h : 2 x 1024 x 10240 fp16           = 41943040  -> 131596288
extern "C" void kernel_launch(void* const* d_in, const int* in_sizes, int n_in,
                              void* d_out, int out_size, void* d_ws, size_t ws_size,
                              hipStream_t stream) {
  (void)in_sizes; (void)n_in; (void)out_size; (void)ws_size;
  const float* fX = (const float*)d_in[0];
  const float* fY = (const float*)d_in[1];
  const float* qX = (const float*)d_in[2];
  const float* qY = (const float*)d_in[3];
  float* out = (float*)d_out;
  char* ws = (char*)d_ws;
  unsigned short* fbf  = (unsigned short*)(ws + 0);
  unsigned short* qT   = (unsigned short*)(ws + 524288);
  unsigned short* nnf  = (unsigned short*)(ws + 67633152);
  unsigned*       cand = (unsigned*)(ws + 72876032);
  unsigned short* sim2 = (unsigned short*)(ws + 89653248);

  hipLaunchKernelGGL(k_norm,  dim3(2048),       dim3(128), 0, stream, fX, fY, out, fbf);
  hipLaunchKernelGGL(k_qcopy, dim3(1024, 2),    dim3(256), 0, stream, qX, qY, out, qT);
  hipLaunchKernelGGL(k_gemm1, dim3(64, 8, 2),   dim3(256), 0, stream, fbf, qT, cand);
  hipLaunchKernelGGL(k_merge, dim3(256, 2),     dim3(256), 0, stream, cand, qT, nnf);
  hipLaunchKernelGGL(k_gemm2, dim3(80, 8, 2),   dim3(256), 0, stream, fbf, nnf, sim2);
  hipLaunchKernelGGL(k_loss,  dim3(1024, 2),    dim3(256), 0, stream, sim2, out);
}